// Round 6
// baseline (317.229 us; speedup 1.0000x reference)
//
#include <hip/hip_runtime.h>
#include <stdint.h>

// Problem constants: B=2, S=2048, D=2048, H=16, HD=128 (multi-query: 1 KV head)
#define BATCH 2
#define SEQ   2048
#define DMOD  2048
#define NHEAD 16
#define HDIM  128

typedef __bf16 bf16x8 __attribute__((ext_vector_type(8)));
typedef float f32x4   __attribute__((ext_vector_type(4)));
typedef float f32x16  __attribute__((ext_vector_type(16)));
typedef unsigned short u16x8 __attribute__((ext_vector_type(8)));

#define MFMA16(a, b, c) __builtin_amdgcn_mfma_f32_16x16x32_bf16(a, b, c, 0, 0, 0)
#define MFMA32(a, b, c) __builtin_amdgcn_mfma_f32_32x32x16_bf16(a, b, c, 0, 0, 0)

__device__ __forceinline__ uint16_t f2bf(float f) {
  union { float f; uint32_t u; } cv; cv.f = f;
  uint32_t u = cv.u;
  return (uint16_t)((u + 0x7FFFu + ((u >> 16) & 1u)) >> 16);  // RNE
}

__device__ __forceinline__ float fexp2(float x) { return exp2f(x); }

__device__ __forceinline__ uint32_t pkbf(float a, float b) {
  uint32_t d;
  asm("v_cvt_pk_bf16_f32 %0, %1, %2" : "=v"(d) : "v"(a), "v"(b));
  return d;  // lo16 = bf16(a), hi16 = bf16(b)
}

__device__ __forceinline__ void gload_lds16(const void* g, void* l) {
  // 16B per lane, LDS dest = wave-uniform base + lane*16 (linear)
  __builtin_amdgcn_global_load_lds(
      (__attribute__((address_space(1))) void*)g,
      (__attribute__((address_space(3))) void*)l, 16, 0, 0);
}

// ---------------- fp32 -> bf16 conversion (vectorized) ----------------
__global__ __launch_bounds__(256) void cvtbf16(const float* __restrict__ in,
                                               uint16_t* __restrict__ out, int n) {
  int i = (blockIdx.x * 256 + threadIdx.x) * 8;
  if (i >= n) return;
  f32x4 a = *(const f32x4*)&in[i];
  f32x4 b = *(const f32x4*)&in[i + 4];
  u16x8 o;
  o[0] = f2bf(a[0]); o[1] = f2bf(a[1]); o[2] = f2bf(a[2]); o[3] = f2bf(a[3]);
  o[4] = f2bf(b[0]); o[5] = f2bf(b[1]); o[6] = f2bf(b[2]); o[7] = f2bf(b[3]);
  *(u16x8*)&out[i] = o;
}

// ---------------- 128x256 pipelined GEMM (tri-buffer, counted vmcnt) ----------
// C[m,n] = (sum_k A[m,k]*W[n,k] + bias[n]) * oscale.  BK=64, 8 waves (2Mx4N),
// per-wave 64x64 output. LDS: 3 buffers x (A 128x64 + B 256x64) bf16 = 144 KB
// (dynamic). Prefetch depth 2 K-tiles; per K-tile: 6 global_load_lds per wave,
// 16 ds_read_b128, 32 MFMA, then s_waitcnt vmcnt(6) + s_barrier (counted wait
// keeps 6 loads in flight across the barrier). XOR swizzle: LDS row = 64 bf16
// (8 x 16B slots), slot ^= row&7 -> 2-way read conflicts (free).
// HAS_KV: blocks 256..287 compute the concat K|V projection (Bkv = 256x2048).
template <bool OUT_F32, bool HAS_KV>
__global__ __launch_bounds__(512, 1) void gemm8(
    const uint16_t* __restrict__ A,
    const uint16_t* __restrict__ Bw, const float* __restrict__ bias,
    void* __restrict__ out, int ldc, float oscale,
    const uint16_t* __restrict__ Bkv,
    const float* __restrict__ biask, const float* __restrict__ biasv,
    uint16_t* __restrict__ kout, uint16_t* __restrict__ vout) {
  extern __shared__ uint16_t smem[];
  uint16_t* As = smem;                  // 3 x 128 x 64
  uint16_t* Bs = smem + 3 * 128 * 64;   // 3 x 256 x 64

  const int lane = threadIdx.x & 63, w = threadIdx.x >> 6;
  const int half = lane >> 4, fr = lane & 15;
  const int wr = w >> 2, wc = w & 3;

  const int f = blockIdx.x;
  bool kvblk = false;
  int m0, n0;
  const uint16_t* Bb;
  if (HAS_KV && f >= 256) {
    kvblk = true; m0 = (f - 256) * 128; n0 = 0; Bb = Bkv;
  } else {
    // XCD-aware 2D chunking: xcd k owns m-group k>>1 (8 m-tiles) x n-group k&1 (4 n-tiles)
    const int xcd = f & 7, idx = f >> 3;
    const int mblk = (xcd >> 1) * 8 + (idx & 7);
    const int nblk = (xcd & 1) * 4 + (idx >> 3);
    m0 = mblk * 128; n0 = nblk * 256; Bb = Bw;
  }

  // staging source offsets (pre-swizzled col, rule 21)
  const int rsub = lane >> 3;                       // within-chunk row 0..7
  const int swcol = ((lane & 7) ^ rsub) * 8;        // inverse-swizzled source col
  const size_t a0 = (size_t)(m0 + (2 * w) * 8 + rsub) * DMOD + swcol;
  const size_t b0 = (size_t)(n0 + (4 * w) * 8 + rsub) * DMOD + swcol;

  f32x4 acc[4][4] = {};
  const int NT = DMOD / 64;  // 32

  auto STAGE = [&](int kt, int slot) {
    uint16_t* Ad = As + slot * (128 * 64);
    uint16_t* Bd = Bs + slot * (256 * 64);
    const int kk = kt * 64;
    gload_lds16(&A[a0 + kk],            &Ad[(2 * w) * 512]);
    gload_lds16(&A[a0 + 8 * DMOD + kk], &Ad[(2 * w + 1) * 512]);
    gload_lds16(&Bb[b0 + kk],             &Bd[(4 * w) * 512]);
    gload_lds16(&Bb[b0 + 8 * DMOD + kk],  &Bd[(4 * w + 1) * 512]);
    gload_lds16(&Bb[b0 + 16 * DMOD + kk], &Bd[(4 * w + 2) * 512]);
    gload_lds16(&Bb[b0 + 24 * DMOD + kk], &Bd[(4 * w + 3) * 512]);
  };

  // prologue: stage tiles 0,1; wait tile 0 (6 of 12 outstanding)
  STAGE(0, 0);
  STAGE(1, 1);
  asm volatile("s_waitcnt vmcnt(6)" ::: "memory");
  __builtin_amdgcn_s_barrier();
  asm volatile("" ::: "memory");

  int sc_ = 0, ss_ = 2;
#pragma unroll 1
  for (int t = 0; t < NT; ++t) {
    if (t + 2 < NT) STAGE(t + 2, ss_);

    const uint16_t* Ar = As + sc_ * (128 * 64);
    const uint16_t* Br = Bs + sc_ * (256 * 64);
#pragma unroll
    for (int kc = 0; kc < 2; ++kc) {
      bf16x8 af[4], bf[4];
      const int slot = ((kc * 4 + half) ^ (fr & 7)) * 8;
#pragma unroll
      for (int i = 0; i < 4; ++i)
        af[i] = *(const bf16x8*)&Ar[(wr * 64 + i * 16 + fr) * 64 + slot];
#pragma unroll
      for (int j = 0; j < 4; ++j)
        bf[j] = *(const bf16x8*)&Br[(wc * 64 + j * 16 + fr) * 64 + slot];
      __builtin_amdgcn_s_setprio(1);
#pragma unroll
      for (int i = 0; i < 4; ++i)
#pragma unroll
        for (int j = 0; j < 4; ++j)
          acc[i][j] = MFMA16(af[i], bf[j], acc[i][j]);
      __builtin_amdgcn_s_setprio(0);
    }

    if (t + 2 < NT) asm volatile("s_waitcnt vmcnt(6)" ::: "memory");
    else            asm volatile("s_waitcnt vmcnt(0)" ::: "memory");
    if (t + 1 < NT) {
      __builtin_amdgcn_s_barrier();
      asm volatile("" ::: "memory");
    }
    sc_ = (sc_ == 2) ? 0 : sc_ + 1;
    ss_ = (ss_ == 2) ? 0 : ss_ + 1;
  }

  // epilogue: C/D layout col = lane&15, row = (lane>>4)*4 + reg
  const float os = kvblk ? 1.0f : oscale;
#pragma unroll
  for (int j = 0; j < 4; ++j) {
    const int col = wc * 64 + j * 16 + fr;  // 0..255
    float bv_;
    if (!kvblk) bv_ = bias[n0 + col];
    else        bv_ = (col < 128) ? biask[col] : biasv[col - 128];
#pragma unroll
    for (int i = 0; i < 4; ++i) {
      const int rowb = m0 + wr * 64 + i * 16 + half * 4;
#pragma unroll
      for (int r = 0; r < 4; ++r) {
        const float v = (acc[i][j][r] + bv_) * os;
        if (!kvblk) {
          if (OUT_F32) ((float*)out)[(size_t)(rowb + r) * ldc + n0 + col] = v;
          else ((uint16_t*)out)[(size_t)(rowb + r) * ldc + n0 + col] = f2bf(v);
        } else {
          if (col < 128) kout[(size_t)(rowb + r) * HDIM + col] = f2bf(v);
          else           vout[(size_t)(rowb + r) * HDIM + col - 128] = f2bf(v);
        }
      }
    }
  }
}

// ---------------- V transpose: (B*S, HD) -> (B, HD, S) ----------------
__global__ __launch_bounds__(256) void transpose_v(const uint16_t* __restrict__ vb,
                                                   uint16_t* __restrict__ vt) {
  __shared__ uint16_t tile[64][65];
  const int s0 = blockIdx.x * 64, d0 = blockIdx.y * 64, b = blockIdx.z;
  const int tx = threadIdx.x & 63, ty = threadIdx.x >> 6;
#pragma unroll
  for (int r = ty; r < 64; r += 4)
    tile[r][tx] = vb[((size_t)b * SEQ + s0 + r) * HDIM + d0 + tx];
  __syncthreads();
#pragma unroll
  for (int r = ty; r < 64; r += 4)
    vt[((size_t)b * HDIM + d0 + r) * SEQ + s0 + tx] = tile[tx][r];
}

// ---------------- flash MQA attention (swapped QK^T, 32x32 MFMA) ----------------
// grid (S/128, H, B), 256 thr (4 waves). Wave w owns 32 q-rows; each lane owns ONE
// q-column (col = lane&31). Swapped QK^T -> per-lane key-scores in registers;
// softmax in-register (log2 domain, no max subtraction). P redistribution to the
// PV B-operand via v_cvt_pk_bf16_f32 + v_permlane32_swap_b32 (no LDS, no cndmask).
// K and V^T double-buffered in XOR-swizzled LDS, one barrier per iteration.
__global__ __launch_bounds__(256, 2) void mqa_attn(
    const uint16_t* __restrict__ qb,   // (B*S, D), pre-scaled by 1/sqrt(HD)*log2e
    const uint16_t* __restrict__ kb,   // (B*S, HD)
    const uint16_t* __restrict__ vt,   // (B, HD, S)
    uint16_t* __restrict__ ab) {       // (B*H*S, HD) contiguous
  __shared__ uint16_t Ks[2][64 * 128];  // [key][d], XOR-swizzled rows
  __shared__ uint16_t Vs[2][128 * 64];  // [d][key], XOR-swizzled rows

  const int t = threadIdx.x, lane = t & 63, w = t >> 6;
  const int l31 = lane & 31, hi = lane >> 5;
  const int qt = blockIdx.x, h = blockIdx.y, b = blockIdx.z;
  const size_t rowbase = (size_t)b * SEQ;
  const int q0 = qt * 128 + w * 32;

  // Q fragments (B operand): col = q = l31, k-chunk c8: d = c8*16 + hi*8 + 0..7
  bf16x8 qf[8];
  {
    const uint16_t* qrow = &qb[(rowbase + q0 + l31) * DMOD + h * HDIM + hi * 8];
#pragma unroll
    for (int c8 = 0; c8 < 8; ++c8)
      qf[c8] = *(const bf16x8*)&qrow[c8 * 16];
  }

  f32x16 ot[4] = {};  // O^T d-tiles: row d = dt*32+(reg&3)+8*(reg>>2)+4*hi, col q = l31
  float lsum = 0.f;

  const int skrow = lane >> 4;        // K: within-chunk row 0..3 (row stride 128)
  const int skcol = (lane & 15) * 8;
  const int svrow = lane >> 3;        // V: within-chunk row 0..7 (row stride 64)
  const int svcol = (lane & 7) * 8;

  // stage tile 0 (linear LDS dest + inverse-swizzled global source)
#pragma unroll
  for (int c = 0; c < 4; ++c) {
    const int ch = c * 4 + w;
    const int krow = ch * 4 + skrow;
    gload_lds16(&kb[(rowbase + krow) * HDIM + (skcol ^ ((krow & 7) << 3))],
                &Ks[0][ch * 512]);
    const int vrow = ch * 8 + svrow;
    gload_lds16(&vt[((size_t)b * HDIM + vrow) * SEQ + (svcol ^ ((vrow & 7) << 3))],
                &Vs[0][ch * 512]);
  }
  __syncthreads();

  for (int kt = 0; kt < SEQ / 64; ++kt) {
    const int cur = kt & 1;
    // prefetch next K/V tiles into the other buffers (land at end-of-iter barrier)
    if (kt < SEQ / 64 - 1) {
#pragma unroll
      for (int c = 0; c < 4; ++c) {
        const int ch = c * 4 + w;
        const int krow = ch * 4 + skrow;
        gload_lds16(&kb[(rowbase + (kt + 1) * 64 + krow) * HDIM +
                        (skcol ^ ((krow & 7) << 3))],
                    &Ks[cur ^ 1][ch * 512]);
        const int vrow = ch * 8 + svrow;
        gload_lds16(&vt[((size_t)b * HDIM + vrow) * SEQ + (kt + 1) * 64 +
                        (svcol ^ ((vrow & 7) << 3))],
                    &Vs[cur ^ 1][ch * 512]);
      }
    }

    // QK^T swapped: st[tt][reg] = S^T[key = tt*32+(reg&3)+8*(reg>>2)+4*hi][q = l31]
    f32x16 st[2] = {};
    __builtin_amdgcn_s_setprio(1);
#pragma unroll
    for (int c8 = 0; c8 < 8; ++c8) {
#pragma unroll
      for (int tt = 0; tt < 2; ++tt) {
        const int krow = tt * 32 + l31;
        bf16x8 kf = *(const bf16x8*)&Ks[cur][krow * 128 +
                        ((c8 * 16 + hi * 8) ^ ((krow & 7) << 3))];
        st[tt] = MFMA32(kf, qf[c8], st[tt]);
      }
    }
    __builtin_amdgcn_s_setprio(0);

    // exp2 (log2-domain, no max subtraction) + bf16 pack + per-q sum
    uint32_t wk[2][8];
    float s = 0.f;
#pragma unroll
    for (int tt = 0; tt < 2; ++tt) {
      float e[16];
#pragma unroll
      for (int i = 0; i < 16; ++i) {
        e[i] = fexp2(st[tt][i]);
        s += e[i];
      }
#pragma unroll
      for (int i = 0; i < 8; ++i)
        wk[tt][i] = pkbf(e[2 * i], e[2 * i + 1]);
    }
    s += __shfl_xor(s, 32);  // partner lane holds the other 32 keys of same q
    lsum += s;

    // P^T fragments via permlane32_swap: swap(a,b): a' = (a.lo, b.lo), b' = (a.hi, b.hi)
    // pf[kc] = P^T[keys kc*16 + hi*8 + 0..7][q = l31]
    bf16x8 pf[4];
#pragma unroll
    for (int tt = 0; tt < 2; ++tt) {
      uint32_t a0 = wk[tt][0], c0 = wk[tt][2];
      uint32_t a1 = wk[tt][1], c1 = wk[tt][3];
      uint32_t a2 = wk[tt][4], c2 = wk[tt][6];
      uint32_t a3 = wk[tt][5], c3 = wk[tt][7];
      asm volatile("v_permlane32_swap_b32 %0, %1" : "+v"(a0), "+v"(c0));
      asm volatile("v_permlane32_swap_b32 %0, %1" : "+v"(a1), "+v"(c1));
      asm volatile("v_permlane32_swap_b32 %0, %1" : "+v"(a2), "+v"(c2));
      asm volatile("v_permlane32_swap_b32 %0, %1" : "+v"(a3), "+v"(c3));
      union { uint32_t u[4]; bf16x8 v; } p0, p1;
      p0.u[0] = a0; p0.u[1] = a1; p0.u[2] = c0; p0.u[3] = c1;
      p1.u[0] = a2; p1.u[1] = a3; p1.u[2] = c2; p1.u[3] = c3;
      pf[2 * tt] = p0.v;
      pf[2 * tt + 1] = p1.v;
    }

    // PV: O^T[d][q] += V^T[d][key] * P^T[key][q]
    __builtin_amdgcn_s_setprio(1);
#pragma unroll
    for (int kc = 0; kc < 4; ++kc) {
#pragma unroll
      for (int dt = 0; dt < 4; ++dt) {
        const int vrow = dt * 32 + l31;
        bf16x8 vf = *(const bf16x8*)&Vs[cur][vrow * 64 +
                        ((kc * 16 + hi * 8) ^ ((vrow & 7) << 3))];
        ot[dt] = MFMA32(vf, pf[kc], ot[dt]);
      }
    }
    __builtin_amdgcn_s_setprio(0);

    __syncthreads();  // drains K/V prefetch (vmcnt) + guards buffer reuse
  }

  // epilogue: normalize by lsum, write (b,h,s,hd)-contiguous (scrambled reshape)
  const float inv = 1.f / lsum;
  const size_t orow = ((size_t)(b * NHEAD + h) * SEQ + q0 + l31) * HDIM;
#pragma unroll
  for (int dt = 0; dt < 4; ++dt)
#pragma unroll
    for (int qd = 0; qd < 4; ++qd) {
      ushort4 hv;
      hv.x = f2bf(ot[dt][qd * 4 + 0] * inv);
      hv.y = f2bf(ot[dt][qd * 4 + 1] * inv);
      hv.z = f2bf(ot[dt][qd * 4 + 2] * inv);
      hv.w = f2bf(ot[dt][qd * 4 + 3] * inv);
      *(ushort4*)&ab[orow + dt * 32 + qd * 8 + hi * 4] = hv;
    }
}

// ---------------- host launch ----------------
extern "C" void kernel_launch(void* const* d_in, const int* in_sizes, int n_in,
                              void* d_out, int out_size, void* d_ws, size_t ws_size,
                              hipStream_t stream) {
  const float* x    = (const float*)d_in[0];
  const float* Wq_w = (const float*)d_in[1];
  const float* Wq_b = (const float*)d_in[2];
  const float* Wk_w = (const float*)d_in[3];
  const float* Wk_b = (const float*)d_in[4];
  const float* Wv_w = (const float*)d_in[5];
  const float* Wv_b = (const float*)d_in[6];
  const float* Wo_w = (const float*)d_in[7];
  const float* Wo_b = (const float*)d_in[8];
  float* out = (float*)d_out;

  char* ws = (char*)d_ws;
  // layout (bytes); xb aliased by ab (xb dead after qkv), wqb aliased by vt
  uint16_t* xb  = (uint16_t*)(ws + 0);         // 16 MB  (B*S, D) bf16
  uint16_t* ab  = xb;                          // 16 MB  (B*H*S, HD) bf16 attn out
  uint16_t* wqb = (uint16_t*)(ws + 16777216);  // 8 MB
  uint16_t* vt  = wqb;                         // 1 MB   (B, HD, S)
  uint16_t* wkb = (uint16_t*)(ws + 25165824);  // 0.5 MB  (contiguous with wvb ->
  uint16_t* wvb = (uint16_t*)(ws + 25690112);  // 0.5 MB   concat [256][2048] KV weight)
  uint16_t* wob = (uint16_t*)(ws + 26214400);  // 8 MB
  uint16_t* qb  = (uint16_t*)(ws + 34603008);  // 16 MB  (B*S, D)
  uint16_t* kb  = (uint16_t*)(ws + 51380224);  // 1 MB   (B*S, HD)
  uint16_t* vb  = (uint16_t*)(ws + 52428800);  // 1 MB   (B*S, HD)
  // total 53,477,376 bytes

  const float qscale = 0.08838834764831845f * 1.4426950408889634f;  // 1/sqrt(128)*log2e
  const int GEMM_LDS = 3 * (128 + 256) * 64 * 2;  // 147456 B

  hipFuncSetAttribute(reinterpret_cast<const void*>(gemm8<false, true>),
                      hipFuncAttributeMaxDynamicSharedMemorySize, GEMM_LDS);
  hipFuncSetAttribute(reinterpret_cast<const void*>(gemm8<true, false>),
                      hipFuncAttributeMaxDynamicSharedMemorySize, GEMM_LDS);

  cvtbf16<<<4096, 256, 0, stream>>>(x, xb, BATCH * SEQ * DMOD);
  cvtbf16<<<2048, 256, 0, stream>>>(Wq_w, wqb, DMOD * DMOD);
  cvtbf16<<<128, 256, 0, stream>>>(Wk_w, wkb, HDIM * DMOD);
  cvtbf16<<<128, 256, 0, stream>>>(Wv_w, wvb, HDIM * DMOD);
  cvtbf16<<<2048, 256, 0, stream>>>(Wo_w, wob, DMOD * DMOD);

  // fused Q projection (256 blocks, XCD-chunked) + KV concat projection (32 tail blocks)
  gemm8<false, true><<<288, 512, GEMM_LDS, stream>>>(
      xb, wqb, Wq_b, qb, DMOD, qscale, wkb, Wk_b, Wv_b, kb, vb);
  transpose_v<<<dim3(32, 2, 2), 256, 0, stream>>>(vb, vt);
  mqa_attn<<<dim3(16, 16, 2), 256, 0, stream>>>(qb, kb, vt, ab);
  gemm8<true, false><<<256, 512, GEMM_LDS, stream>>>(
      ab, wob, Wo_b, out, DMOD, 1.0f, nullptr, nullptr, nullptr, nullptr, nullptr);
}

// Round 7
// 292.711 us; speedup vs baseline: 1.0838x; 1.0838x over previous
//
#include <hip/hip_runtime.h>
#include <stdint.h>

// Problem constants: B=2, S=2048, D=2048, H=16, HD=128 (multi-query: 1 KV head)
#define BATCH 2
#define SEQ   2048
#define DMOD  2048
#define NHEAD 16
#define HDIM  128
#define QKVN  2304   // unified Q|K|V output columns

typedef __bf16 bf16x8 __attribute__((ext_vector_type(8)));
typedef float f32x4   __attribute__((ext_vector_type(4)));
typedef float f32x16  __attribute__((ext_vector_type(16)));
typedef unsigned short u16x8 __attribute__((ext_vector_type(8)));

#define MFMA16(a, b, c) __builtin_amdgcn_mfma_f32_16x16x32_bf16(a, b, c, 0, 0, 0)
#define MFMA32(a, b, c) __builtin_amdgcn_mfma_f32_32x32x16_bf16(a, b, c, 0, 0, 0)

__device__ __forceinline__ uint16_t f2bf(float f) {
  union { float f; uint32_t u; } cv; cv.f = f;
  uint32_t u = cv.u;
  return (uint16_t)((u + 0x7FFFu + ((u >> 16) & 1u)) >> 16);  // RNE
}

__device__ __forceinline__ float fexp2(float x) { return exp2f(x); }

__device__ __forceinline__ uint32_t pkbf(float a, float b) {
  uint32_t d;
  asm("v_cvt_pk_bf16_f32 %0, %1, %2" : "=v"(d) : "v"(a), "v"(b));
  return d;  // lo16 = bf16(a), hi16 = bf16(b)
}

__device__ __forceinline__ void gload_lds16(const void* g, void* l) {
  // 16B per lane, LDS dest = wave-uniform base + lane*16 (linear)
  __builtin_amdgcn_global_load_lds(
      (__attribute__((address_space(1))) void*)g,
      (__attribute__((address_space(3))) void*)l, 16, 0, 0);
}

// ---------------- fp32 -> bf16 conversion (vectorized) ----------------
__global__ __launch_bounds__(256) void cvtbf16(const float* __restrict__ in,
                                               uint16_t* __restrict__ out, int n) {
  int i = (blockIdx.x * 256 + threadIdx.x) * 8;
  if (i >= n) return;
  f32x4 a = *(const f32x4*)&in[i];
  f32x4 b = *(const f32x4*)&in[i + 4];
  u16x8 o;
  o[0] = f2bf(a[0]); o[1] = f2bf(a[1]); o[2] = f2bf(a[2]); o[3] = f2bf(a[3]);
  o[4] = f2bf(b[0]); o[5] = f2bf(b[1]); o[6] = f2bf(b[2]); o[7] = f2bf(b[3]);
  *(u16x8*)&out[i] = o;
}

// ---------------- unified QKV GEMM: 128x192 tiles, 2 blocks/CU ----------------
// out[m, n] over n in [0,2304): cols <2048 are Q (scaled by qscale), 2048..2175 K,
// 2176..2303 V. W = unified weights (2304 rows x 2048), row = output col.
// 8 waves (2M x 4N), per-wave 64x48. Double-buffer BK=64, LDS 80 KB -> 2 blocks/CU
// (4 waves/SIMD). Grid 384 = 32m x 12n, n-major: f%8 = m%8 -> A-panels pinned per
// XCD across all n-panels (L2-resident). vmcnt(0) per K-tile (min-2-phase recipe).
__global__ __launch_bounds__(512, 4) void qkv_gemm2(
    const uint16_t* __restrict__ A,   // (4096, 2048)
    const uint16_t* __restrict__ W,   // (2304, 2048)
    const float* __restrict__ bq, const float* __restrict__ bk,
    const float* __restrict__ bv,
    uint16_t* __restrict__ out,       // (4096, 2304)
    float qscale) {
  extern __shared__ uint16_t smem[];
  uint16_t* As = smem;                  // 2 x 128 x 64
  uint16_t* Bs = smem + 2 * 128 * 64;   // 2 x 192 x 64

  const int lane = threadIdx.x & 63, w = threadIdx.x >> 6;
  const int half = lane >> 4, fr = lane & 15;
  const int wr = w >> 2, wc = w & 3;

  const int f = blockIdx.x;
  const int m0 = (f & 31) * 128;
  const int n0 = (f >> 5) * 192;

  // staging source (pre-swizzled col, rule 21): chunk = 8 rows x 64 cols
  const int rsub = lane >> 3;                 // row within chunk 0..7
  const int swcol = ((lane & 7) ^ rsub) * 8;  // inverse-swizzled source col
  // wave w stages A chunks {2w, 2w+1}, B chunks {3w, 3w+1, 3w+2}
  const size_t a0 = (size_t)(m0 + 2 * w * 8 + rsub) * DMOD + swcol;
  const size_t b0 = (size_t)(n0 + 3 * w * 8 + rsub) * DMOD + swcol;

  f32x4 acc[4][3] = {};
  const int NT = DMOD / 64;  // 32

  auto STAGE = [&](int kt, int buf) {
    uint16_t* Ad = As + buf * (128 * 64);
    uint16_t* Bd = Bs + buf * (192 * 64);
    const int kk = kt * 64;
    gload_lds16(&A[a0 + kk],            &Ad[(2 * w) * 512]);
    gload_lds16(&A[a0 + 8 * DMOD + kk], &Ad[(2 * w + 1) * 512]);
    gload_lds16(&W[b0 + kk],             &Bd[(3 * w) * 512]);
    gload_lds16(&W[b0 + 8 * DMOD + kk],  &Bd[(3 * w + 1) * 512]);
    gload_lds16(&W[b0 + 16 * DMOD + kk], &Bd[(3 * w + 2) * 512]);
  };

  STAGE(0, 0);
  asm volatile("s_waitcnt vmcnt(0)" ::: "memory");
  __builtin_amdgcn_s_barrier();

#pragma unroll 1
  for (int t = 0; t < NT; ++t) {
    const int cur = t & 1;
    if (t + 1 < NT) STAGE(t + 1, cur ^ 1);

    const uint16_t* Ar = As + cur * (128 * 64);
    const uint16_t* Br = Bs + cur * (192 * 64);
#pragma unroll
    for (int kc = 0; kc < 2; ++kc) {
      bf16x8 af[4], bf[3];
      const int slot = ((kc * 4 + half) ^ (fr & 7)) * 8;
#pragma unroll
      for (int i = 0; i < 4; ++i)
        af[i] = *(const bf16x8*)&Ar[(wr * 64 + i * 16 + fr) * 64 + slot];
#pragma unroll
      for (int j = 0; j < 3; ++j)
        bf[j] = *(const bf16x8*)&Br[(wc * 48 + j * 16 + fr) * 64 + slot];
      __builtin_amdgcn_s_setprio(1);
#pragma unroll
      for (int i = 0; i < 4; ++i)
#pragma unroll
        for (int j = 0; j < 3; ++j)
          acc[i][j] = MFMA16(af[i], bf[j], acc[i][j]);
      __builtin_amdgcn_s_setprio(0);
    }

    if (t + 1 < NT) {
      asm volatile("s_waitcnt vmcnt(0)" ::: "memory");
      __builtin_amdgcn_s_barrier();
    }
  }

  // epilogue: C/D col = lane&15, row = (lane>>4)*4 + reg
#pragma unroll
  for (int j = 0; j < 3; ++j) {
    const int col = n0 + wc * 48 + j * 16 + fr;
    float bv_, os_;
    if (col < DMOD)            { bv_ = bq[col];        os_ = qscale; }
    else if (col < DMOD + 128) { bv_ = bk[col - DMOD]; os_ = 1.0f; }
    else                       { bv_ = bv[col - DMOD - 128]; os_ = 1.0f; }
#pragma unroll
    for (int i = 0; i < 4; ++i) {
      const int rowb = m0 + wr * 64 + i * 16 + half * 4;
#pragma unroll
      for (int r = 0; r < 4; ++r)
        out[(size_t)(rowb + r) * QKVN + col] = f2bf((acc[i][j][r] + bv_) * os_);
    }
  }
}

// ---------------- O-projection GEMM (round-6 tri-buffer, n-major map) ---------
__global__ __launch_bounds__(512, 1) void o_gemm(
    const uint16_t* __restrict__ A,
    const uint16_t* __restrict__ Bw, const float* __restrict__ bias,
    float* __restrict__ out) {
  extern __shared__ uint16_t smem[];
  uint16_t* As = smem;                  // 3 x 128 x 64
  uint16_t* Bs = smem + 3 * 128 * 64;   // 3 x 256 x 64

  const int lane = threadIdx.x & 63, w = threadIdx.x >> 6;
  const int half = lane >> 4, fr = lane & 15;
  const int wr = w >> 2, wc = w & 3;

  const int f = blockIdx.x;
  const int m0 = (f & 31) * 128;   // n-major: f%8 = m%8 -> A pinned per XCD
  const int n0 = (f >> 5) * 256;

  const int rsub = lane >> 3;
  const int swcol = ((lane & 7) ^ rsub) * 8;
  const size_t a0 = (size_t)(m0 + (2 * w) * 8 + rsub) * DMOD + swcol;
  const size_t b0 = (size_t)(n0 + (4 * w) * 8 + rsub) * DMOD + swcol;

  f32x4 acc[4][4] = {};
  const int NT = DMOD / 64;  // 32

  auto STAGE = [&](int kt, int slot) {
    uint16_t* Ad = As + slot * (128 * 64);
    uint16_t* Bd = Bs + slot * (256 * 64);
    const int kk = kt * 64;
    gload_lds16(&A[a0 + kk],            &Ad[(2 * w) * 512]);
    gload_lds16(&A[a0 + 8 * DMOD + kk], &Ad[(2 * w + 1) * 512]);
    gload_lds16(&Bw[b0 + kk],             &Bd[(4 * w) * 512]);
    gload_lds16(&Bw[b0 + 8 * DMOD + kk],  &Bd[(4 * w + 1) * 512]);
    gload_lds16(&Bw[b0 + 16 * DMOD + kk], &Bd[(4 * w + 2) * 512]);
    gload_lds16(&Bw[b0 + 24 * DMOD + kk], &Bd[(4 * w + 3) * 512]);
  };

  STAGE(0, 0);
  STAGE(1, 1);
  asm volatile("s_waitcnt vmcnt(6)" ::: "memory");
  __builtin_amdgcn_s_barrier();

  int sc_ = 0, ss_ = 2;
#pragma unroll 1
  for (int t = 0; t < NT; ++t) {
    if (t + 2 < NT) STAGE(t + 2, ss_);

    const uint16_t* Ar = As + sc_ * (128 * 64);
    const uint16_t* Br = Bs + sc_ * (256 * 64);
#pragma unroll
    for (int kc = 0; kc < 2; ++kc) {
      bf16x8 af[4], bf[4];
      const int slot = ((kc * 4 + half) ^ (fr & 7)) * 8;
#pragma unroll
      for (int i = 0; i < 4; ++i)
        af[i] = *(const bf16x8*)&Ar[(wr * 64 + i * 16 + fr) * 64 + slot];
#pragma unroll
      for (int j = 0; j < 4; ++j)
        bf[j] = *(const bf16x8*)&Br[(wc * 64 + j * 16 + fr) * 64 + slot];
      __builtin_amdgcn_s_setprio(1);
#pragma unroll
      for (int i = 0; i < 4; ++i)
#pragma unroll
        for (int j = 0; j < 4; ++j)
          acc[i][j] = MFMA16(af[i], bf[j], acc[i][j]);
      __builtin_amdgcn_s_setprio(0);
    }

    if (t + 2 < NT) asm volatile("s_waitcnt vmcnt(6)" ::: "memory");
    else            asm volatile("s_waitcnt vmcnt(0)" ::: "memory");
    if (t + 1 < NT) __builtin_amdgcn_s_barrier();
    sc_ = (sc_ == 2) ? 0 : sc_ + 1;
    ss_ = (ss_ == 2) ? 0 : ss_ + 1;
  }

#pragma unroll
  for (int j = 0; j < 4; ++j) {
    const int col = wc * 64 + j * 16 + fr;
    const float bv_ = bias[n0 + col];
#pragma unroll
    for (int i = 0; i < 4; ++i) {
      const int rowb = m0 + wr * 64 + i * 16 + half * 4;
#pragma unroll
      for (int r = 0; r < 4; ++r)
        out[(size_t)(rowb + r) * DMOD + n0 + col] = acc[i][j][r] + bv_;
    }
  }
}

// ---------------- V transpose: qkv_u V-cols -> (B, HD, S) ----------------
__global__ __launch_bounds__(256) void transpose_v(const uint16_t* __restrict__ qkv,
                                                   uint16_t* __restrict__ vt) {
  __shared__ uint16_t tile[64][65];
  const int s0 = blockIdx.x * 64, d0 = blockIdx.y * 64, b = blockIdx.z;
  const int tx = threadIdx.x & 63, ty = threadIdx.x >> 6;
#pragma unroll
  for (int r = ty; r < 64; r += 4)
    tile[r][tx] = qkv[((size_t)b * SEQ + s0 + r) * QKVN + (DMOD + 128) + d0 + tx];
  __syncthreads();
#pragma unroll
  for (int r = ty; r < 64; r += 4)
    vt[((size_t)b * HDIM + d0 + r) * SEQ + s0 + tx] = tile[tx][r];
}

// ---------------- flash MQA attention (8 heads share K/V staging) -------------
// grid (S/32, H/8, B), 512 thr (8 waves). Wave w = head hg*8+w, 32 q-rows
// (q0 = qt*32); all 8 waves share the K/V LDS tiles (MQA: 1 KV head).
// Swapped QK^T (32x32 MFMA) -> per-lane key-scores in registers; softmax
// in-register (log2 domain, no max subtraction); P via cvt_pk + permlane32_swap.
// K and V^T double-buffered in XOR-swizzled LDS, one barrier per iteration.
__global__ __launch_bounds__(512, 2) void mqa_attn(
    const uint16_t* __restrict__ qkv,  // (B*S, 2304): Q pre-scaled, K at +2048
    const uint16_t* __restrict__ vt,   // (B, HD, S)
    uint16_t* __restrict__ ab) {       // (B*H*S, HD) contiguous
  __shared__ uint16_t Ks[2][64 * 128];  // [key][d], XOR-swizzled rows
  __shared__ uint16_t Vs[2][128 * 64];  // [d][key], XOR-swizzled rows

  const int t = threadIdx.x, lane = t & 63, w = t >> 6;
  const int l31 = lane & 31, hi = lane >> 5;
  const int qt = blockIdx.x, hg = blockIdx.y, b = blockIdx.z;
  const int h = hg * 8 + w;
  const size_t rowbase = (size_t)b * SEQ;
  const int q0 = qt * 32;

  // Q fragments (B operand): col = q = l31, k-chunk c8: d = c8*16 + hi*8 + 0..7
  bf16x8 qf[8];
  {
    const uint16_t* qrow = &qkv[(rowbase + q0 + l31) * QKVN + h * HDIM + hi * 8];
#pragma unroll
    for (int c8 = 0; c8 < 8; ++c8)
      qf[c8] = *(const bf16x8*)&qrow[c8 * 16];
  }

  f32x16 ot[4] = {};  // O^T d-tiles: row d = dt*32+(reg&3)+8*(reg>>2)+4*hi, col q = l31
  float lsum = 0.f;

  const int skrow = lane >> 4;        // K: within-chunk row 0..3 (row stride 128)
  const int skcol = (lane & 15) * 8;
  const int svrow = lane >> 3;        // V: within-chunk row 0..7 (row stride 64)
  const int svcol = (lane & 7) * 8;

  // stage tile 0: 16 K-chunks + 16 V-chunks over 8 waves (2+2 each)
#pragma unroll
  for (int c = 0; c < 2; ++c) {
    const int ch = 2 * w + c;
    const int krow = ch * 4 + skrow;
    gload_lds16(&qkv[(rowbase + krow) * QKVN + DMOD + (skcol ^ ((krow & 7) << 3))],
                &Ks[0][ch * 512]);
    const int vrow = ch * 8 + svrow;
    gload_lds16(&vt[((size_t)b * HDIM + vrow) * SEQ + (svcol ^ ((vrow & 7) << 3))],
                &Vs[0][ch * 512]);
  }
  __syncthreads();

  for (int kt = 0; kt < SEQ / 64; ++kt) {
    const int cur = kt & 1;
    if (kt < SEQ / 64 - 1) {
#pragma unroll
      for (int c = 0; c < 2; ++c) {
        const int ch = 2 * w + c;
        const int krow = ch * 4 + skrow;
        gload_lds16(&qkv[(rowbase + (kt + 1) * 64 + krow) * QKVN + DMOD +
                         (skcol ^ ((krow & 7) << 3))],
                    &Ks[cur ^ 1][ch * 512]);
        const int vrow = ch * 8 + svrow;
        gload_lds16(&vt[((size_t)b * HDIM + vrow) * SEQ + (kt + 1) * 64 +
                        (svcol ^ ((vrow & 7) << 3))],
                    &Vs[cur ^ 1][ch * 512]);
      }
    }

    // QK^T swapped: st[tt][reg] = S^T[key = tt*32+(reg&3)+8*(reg>>2)+4*hi][q = l31]
    f32x16 st[2] = {};
    __builtin_amdgcn_s_setprio(1);
#pragma unroll
    for (int c8 = 0; c8 < 8; ++c8) {
#pragma unroll
      for (int tt = 0; tt < 2; ++tt) {
        const int krow = tt * 32 + l31;
        bf16x8 kf = *(const bf16x8*)&Ks[cur][krow * 128 +
                        ((c8 * 16 + hi * 8) ^ ((krow & 7) << 3))];
        st[tt] = MFMA32(kf, qf[c8], st[tt]);
      }
    }
    __builtin_amdgcn_s_setprio(0);

    // exp2 (log2-domain) + bf16 pack + per-q sum
    uint32_t wk[2][8];
    float s = 0.f;
#pragma unroll
    for (int tt = 0; tt < 2; ++tt) {
      float e[16];
#pragma unroll
      for (int i = 0; i < 16; ++i) {
        e[i] = fexp2(st[tt][i]);
        s += e[i];
      }
#pragma unroll
      for (int i = 0; i < 8; ++i)
        wk[tt][i] = pkbf(e[2 * i], e[2 * i + 1]);
    }
    s += __shfl_xor(s, 32);
    lsum += s;

    // P^T fragments via permlane32_swap
    bf16x8 pf[4];
#pragma unroll
    for (int tt = 0; tt < 2; ++tt) {
      uint32_t a0 = wk[tt][0], c0 = wk[tt][2];
      uint32_t a1 = wk[tt][1], c1 = wk[tt][3];
      uint32_t a2 = wk[tt][4], c2 = wk[tt][6];
      uint32_t a3 = wk[tt][5], c3 = wk[tt][7];
      asm volatile("v_permlane32_swap_b32 %0, %1" : "+v"(a0), "+v"(c0));
      asm volatile("v_permlane32_swap_b32 %0, %1" : "+v"(a1), "+v"(c1));
      asm volatile("v_permlane32_swap_b32 %0, %1" : "+v"(a2), "+v"(c2));
      asm volatile("v_permlane32_swap_b32 %0, %1" : "+v"(a3), "+v"(c3));
      union { uint32_t u[4]; bf16x8 v; } p0, p1;
      p0.u[0] = a0; p0.u[1] = a1; p0.u[2] = c0; p0.u[3] = c1;
      p1.u[0] = a2; p1.u[1] = a3; p1.u[2] = c2; p1.u[3] = c3;
      pf[2 * tt] = p0.v;
      pf[2 * tt + 1] = p1.v;
    }

    // PV: O^T[d][q] += V^T[d][key] * P^T[key][q]
    __builtin_amdgcn_s_setprio(1);
#pragma unroll
    for (int kc = 0; kc < 4; ++kc) {
#pragma unroll
      for (int dt = 0; dt < 4; ++dt) {
        const int vrow = dt * 32 + l31;
        bf16x8 vf = *(const bf16x8*)&Vs[cur][vrow * 64 +
                        ((kc * 16 + hi * 8) ^ ((vrow & 7) << 3))];
        ot[dt] = MFMA32(vf, pf[kc], ot[dt]);
      }
    }
    __builtin_amdgcn_s_setprio(0);

    __syncthreads();  // drains K/V prefetch (vmcnt) + guards buffer reuse
  }

  // epilogue: normalize, write (b,h,s,hd)-contiguous (scrambled reshape)
  const float inv = 1.f / lsum;
  const size_t orow = ((size_t)(b * NHEAD + h) * SEQ + q0 + l31) * HDIM;
#pragma unroll
  for (int dt = 0; dt < 4; ++dt)
#pragma unroll
    for (int qd = 0; qd < 4; ++qd) {
      ushort4 hv;
      hv.x = f2bf(ot[dt][qd * 4 + 0] * inv);
      hv.y = f2bf(ot[dt][qd * 4 + 1] * inv);
      hv.z = f2bf(ot[dt][qd * 4 + 2] * inv);
      hv.w = f2bf(ot[dt][qd * 4 + 3] * inv);
      *(ushort4*)&ab[orow + dt * 32 + qd * 8 + hi * 4] = hv;
    }
}

// ---------------- host launch ----------------
extern "C" void kernel_launch(void* const* d_in, const int* in_sizes, int n_in,
                              void* d_out, int out_size, void* d_ws, size_t ws_size,
                              hipStream_t stream) {
  const float* x    = (const float*)d_in[0];
  const float* Wq_w = (const float*)d_in[1];
  const float* Wq_b = (const float*)d_in[2];
  const float* Wk_w = (const float*)d_in[3];
  const float* Wk_b = (const float*)d_in[4];
  const float* Wv_w = (const float*)d_in[5];
  const float* Wv_b = (const float*)d_in[6];
  const float* Wo_w = (const float*)d_in[7];
  const float* Wo_b = (const float*)d_in[8];
  float* out = (float*)d_out;

  char* ws = (char*)d_ws;
  // layout (bytes); ab aliases xb (dead after qkv); vt aliases wqb (dead after qkv)
  uint16_t* xb    = (uint16_t*)(ws + 0);         // 16 MB  (B*S, D) bf16
  uint16_t* ab    = xb;                          // 16 MB  (B*H*S, HD) attn out
  uint16_t* wqb   = (uint16_t*)(ws + 16777216);  // 8 MB   } contiguous ->
  uint16_t* vt    = wqb;                         // 1 MB   (B, HD, S), post-qkv
  uint16_t* wkb   = (uint16_t*)(ws + 25165824);  // 0.5 MB } unified (2304,2048)
  uint16_t* wvb   = (uint16_t*)(ws + 25690112);  // 0.5 MB } weight matrix
  uint16_t* wob   = (uint16_t*)(ws + 26214400);  // 8 MB
  uint16_t* qkv_u = (uint16_t*)(ws + 34603008);  // 18 MB  (B*S, 2304) bf16
  // total 53,477,376 bytes

  const float qscale = 0.08838834764831845f * 1.4426950408889634f;  // 1/sqrt(128)*log2e
  const int QKV_LDS = 2 * (128 + 192) * 64 * 2;  // 81920 B
  const int O_LDS   = 3 * (128 + 256) * 64 * 2;  // 147456 B

  hipFuncSetAttribute(reinterpret_cast<const void*>(qkv_gemm2),
                      hipFuncAttributeMaxDynamicSharedMemorySize, QKV_LDS);
  hipFuncSetAttribute(reinterpret_cast<const void*>(o_gemm),
                      hipFuncAttributeMaxDynamicSharedMemorySize, O_LDS);

  cvtbf16<<<4096, 256, 0, stream>>>(x, xb, BATCH * SEQ * DMOD);
  cvtbf16<<<2048, 256, 0, stream>>>(Wq_w, wqb, DMOD * DMOD);
  cvtbf16<<<128, 256, 0, stream>>>(Wk_w, wkb, HDIM * DMOD);
  cvtbf16<<<128, 256, 0, stream>>>(Wv_w, wvb, HDIM * DMOD);
  cvtbf16<<<2048, 256, 0, stream>>>(Wo_w, wob, DMOD * DMOD);

  qkv_gemm2<<<384, 512, QKV_LDS, stream>>>(xb, wqb, Wq_b, Wk_b, Wv_b, qkv_u, qscale);
  transpose_v<<<dim3(32, 2, 2), 256, 0, stream>>>(qkv_u, vt);
  mqa_attn<<<dim3(64, 2, 2), 512, 0, stream>>>(qkv_u, vt, ab);
  o_gemm<<<256, 512, O_LDS, stream>>>(ab, wob, Wo_b, out);
}